// Round 2
// baseline (426.219 us; speedup 1.0000x reference)
//
#include <hip/hip_runtime.h>

#define HIDDEN 2048
#define INTER  5632
#define TOKENS 4096

#define BK 64
#define GROUP_N 4

// gemm1 tile (fused gate+up): 256x128, dbuf LDS 128KB, 512 thr, 1 blk/CU
#define BM1 256
#define BN1 128
#define NT1 (HIDDEN / BK)   // 32 K-tiles

// gemm2 tile: 256x128, dbuf LDS 96KB, 512 thr, 1 blk/CU, grid 256 = no tail
#define BM2 256
#define BN2 128
#define NT2 (INTER / BK)    // 88 K-tiles

using bf16x8 = __attribute__((ext_vector_type(8))) __bf16;
using f32x4  = __attribute__((ext_vector_type(4))) float;

__device__ __forceinline__ unsigned short f2bf(float f) {
    unsigned int u = __float_as_uint(f);
    u += 0x7FFFu + ((u >> 16) & 1u);
    return (unsigned short)(u >> 16);
}

#define GLDS(gptr, lptr) \
    __builtin_amdgcn_global_load_lds((__attribute__((address_space(1))) void*)(gptr), \
                                     (__attribute__((address_space(3))) void*)(lptr), 16, 0, 0)

// ---------------- prep: dequant (LDS-cached codebook) + cast x ----------------
// R7-verified (-16 us vs divergent-gather version).
__global__ __launch_bounds__(512) void prep_kernel(
        const float* __restrict__ x, unsigned short* __restrict__ xb,
        const int* __restrict__ ig, const float* __restrict__ cbg,
        const float* __restrict__ sg, unsigned short* __restrict__ wg,
        const int* __restrict__ iu, const float* __restrict__ cbu,
        const float* __restrict__ su, unsigned short* __restrict__ wu,
        const int* __restrict__ idn, const float* __restrict__ cbd,
        const float* __restrict__ sd, unsigned short* __restrict__ wd) {
    __shared__ unsigned short cbl[4096 * 8];   // 64 KB bf16 codebook
    const int b = blockIdx.x;
    const int tid = threadIdx.x;

    if (b >= 528) {                            // ---- cast x ----
        int t = (b - 528) * 512 + tid;
        const float4* x4 = (const float4*)x;
        float4 a = x4[2 * t];
        float4 c = x4[2 * t + 1];
        uint4 o;
        o.x = f2bf(a.x) | ((unsigned int)f2bf(a.y) << 16);
        o.y = f2bf(a.z) | ((unsigned int)f2bf(a.w) << 16);
        o.z = f2bf(c.x) | ((unsigned int)f2bf(c.y) << 16);
        o.w = f2bf(c.z) | ((unsigned int)f2bf(c.w) << 16);
        ((uint4*)xb)[t] = o;
        return;
    }

    const int mat = b / 176;
    const int bl  = b % 176;
    const int* idx; const float* cb; const float* scale; unsigned short* w; int ncol8;
    if (mat == 0)      { idx = ig;  cb = cbg; scale = sg; w = wg; ncol8 = HIDDEN / 8; }
    else if (mat == 1) { idx = iu;  cb = cbu; scale = su; w = wu; ncol8 = HIDDEN / 8; }
    else               { idx = idn; cb = cbd; scale = sd; w = wd; ncol8 = INTER / 8; }

#pragma unroll
    for (int i = 0; i < 8; ++i) {
        int r = i * 512 + tid;
        const float4* c4 = (const float4*)(cb + ((size_t)r << 3));
        float4 a = c4[0];
        float4 c = c4[1];
        uint4 o;
        o.x = f2bf(a.x) | ((unsigned int)f2bf(a.y) << 16);
        o.y = f2bf(a.z) | ((unsigned int)f2bf(a.w) << 16);
        o.z = f2bf(c.x) | ((unsigned int)f2bf(c.y) << 16);
        o.w = f2bf(c.z) | ((unsigned int)f2bf(c.w) << 16);
        ((uint4*)cbl)[r] = o;
    }
    __syncthreads();

    const size_t base = (size_t)bl * 8192;
#pragma unroll 2
    for (int i = 0; i < 16; ++i) {
        size_t t = base + i * 512 + tid;
        int id = idx[t];
        float s = scale[t / ncol8];
        const unsigned short* cw = cbl + ((unsigned)id << 3);
        uint4 cv = *(const uint4*)cw;
        unsigned int ww[4];
#pragma unroll
        for (int j = 0; j < 4; ++j) {
            unsigned int pair = (&cv.x)[j];
            float lo = __uint_as_float(pair << 16) * s;
            float hi = __uint_as_float(pair & 0xFFFF0000u) * s;
            ww[j] = f2bf(lo) | ((unsigned int)f2bf(hi) << 16);
        }
        uint4 o = {ww[0], ww[1], ww[2], ww[3]};
        ((uint4*)w)[t] = o;
    }
}

// Journal:
// R2: XOR-swizzle verified conflict-free w/ 16x16 frags. R5: group-raster
//   FETCH -30%. R8: 32x32 frags bank-conflict at BK=64 — 16x16 only.
// R3: (256,3) gemm1 spills. R4: BK=32 dbuf regressed. R6: barrier-free
//   glds->ds_read UNSAFE.
// R9 FAILED: 8-phase port (9 barriers/K-tile, 16-MFMA clusters, 2 w/SIMD)
//   = m232's documented failure quadrant. MfmaUtil 48->31, 176->252us.
//   Lesson: fine-phase barriers need m201's exact derived-waits schedule.
// R10 (this round): "minimum 2-phase" (m248v2/m230-verified): issue
//   next-tile STAGE *before* compute, ONE __syncthreads per K-tile (its
//   vmcnt(0) waits for loads that had the whole compute phase in flight).
//   Tiles grown to 256x128 (compute:stage cycle ratio 1.18 -> 1.77 gemm1;
//   0.89 -> 1.18 gemm2) so staging hides under compute even at 1 blk/CU.
__device__ __forceinline__ void decode_block(int bid, int nblocks_m, int nblocks_n,
                                             int* mb, int* nb) {
    int gw = nblocks_m * GROUP_N;
    int group = bid / gw;
    int inb = bid % gw;
    int gn = group * GROUP_N;
    int width = (nblocks_n - gn < GROUP_N) ? (nblocks_n - gn) : GROUP_N;
    *mb = inb / width;
    *nb = gn + inb % width;
}

// ---------------- GEMM1: H = silu(X Wg^T) * (X Wu^T), bf16 out ----------------
__global__ __launch_bounds__(512, 2) void gemm1_kernel(const unsigned short* __restrict__ X,
                                                       const unsigned short* __restrict__ Wg,
                                                       const unsigned short* __restrict__ Wu,
                                                       unsigned short* __restrict__ H) {
    __shared__ unsigned short As[2][BM1 * BK];    // 64 KB
    __shared__ unsigned short Bgs[2][BN1 * BK];   // 32 KB
    __shared__ unsigned short Bus[2][BN1 * BK];   // 32 KB

    const int tid  = threadIdx.x;
    const int lane = tid & 63;
    const int wave = tid >> 6;
    int mb, nb;
    decode_block(blockIdx.x, TOKENS / BM1, INTER / BN1, &mb, &nb);
    const int m0 = mb * BM1;
    const int n0 = nb * BN1;

    // staging: 512 threads x 16B; swizzle on GLOBAL column chunk
    // (pre-swizzled source, LDS lane-linear — glds constraint).
    const int srow = tid >> 3;
    const int scol = (tid & 7) << 3;
    const int gcol = (((tid & 7) ^ (srow & 7))) << 3;

    const int wr = wave >> 1;     // 0..3 (M, 64-row chunks)
    const int wc = wave & 1;      // 0..1 (N, 64-col chunks)
    const int ln15 = lane & 15;
    const int lq = lane >> 4;
    const int swr = ln15 & 7;

    f32x4 accg[4][4], accu[4][4];
    const f32x4 z = {0.f, 0.f, 0.f, 0.f};
    for (int i = 0; i < 4; ++i)
        for (int j = 0; j < 4; ++j) { accg[i][j] = z; accu[i][j] = z; }

    // 8 GLDS per thread per K-tile: A x4, Bg x2, Bu x2
#define STAGE1(buf, kt) do {                                                        \
        const int k0_ = (kt) * BK;                                                  \
        _Pragma("unroll")                                                           \
        for (int i_ = 0; i_ < 4; ++i_) {                                            \
            const int r_ = i_ * 64 + srow;                                          \
            GLDS(X + (size_t)(m0 + r_) * HIDDEN + k0_ + gcol,                       \
                 &As[buf][r_ * BK + scol]);                                         \
        }                                                                           \
        _Pragma("unroll")                                                           \
        for (int i_ = 0; i_ < 2; ++i_) {                                            \
            const int r_ = i_ * 64 + srow;                                          \
            GLDS(Wg + (size_t)(n0 + r_) * HIDDEN + k0_ + gcol,                      \
                 &Bgs[buf][r_ * BK + scol]);                                        \
            GLDS(Wu + (size_t)(n0 + r_) * HIDDEN + k0_ + gcol,                      \
                 &Bus[buf][r_ * BK + scol]);                                        \
        }                                                                           \
    } while (0)

    STAGE1(0, 0);
    __syncthreads();                       // vmcnt(0): tile 0 landed

    for (int t = 0; t < NT1; ++t) {
        const int cur = t & 1;
        if (t + 1 < NT1) STAGE1(cur ^ 1, t + 1);   // overlaps entire compute
#pragma unroll
        for (int ks = 0; ks < 2; ++ks) {
            const int pofs = (((ks * 4 + lq) ^ swr)) << 3;
            bf16x8 af[4], bg[4], bu[4];
#pragma unroll
            for (int im = 0; im < 4; ++im)
                af[im] = *(const bf16x8*)(&As[cur][(wr * 64 + im * 16 + ln15) * BK + pofs]);
#pragma unroll
            for (int in = 0; in < 4; ++in) {
                bg[in] = *(const bf16x8*)(&Bgs[cur][(wc * 64 + in * 16 + ln15) * BK + pofs]);
                bu[in] = *(const bf16x8*)(&Bus[cur][(wc * 64 + in * 16 + ln15) * BK + pofs]);
            }
#pragma unroll
            for (int im = 0; im < 4; ++im)
#pragma unroll
                for (int in = 0; in < 4; ++in) {
                    accg[im][in] = __builtin_amdgcn_mfma_f32_16x16x32_bf16(af[im], bg[in], accg[im][in], 0, 0, 0);
                    accu[im][in] = __builtin_amdgcn_mfma_f32_16x16x32_bf16(af[im], bu[in], accu[im][in], 0, 0, 0);
                }
        }
        __syncthreads();   // vmcnt(0)+barrier: next tile ready, buf[cur] free
    }
#undef STAGE1

#pragma unroll
    for (int im = 0; im < 4; ++im)
#pragma unroll
        for (int in = 0; in < 4; ++in) {
            const int row = m0 + wr * 64 + im * 16 + lq * 4;
            const int col = n0 + wc * 64 + in * 16 + ln15;
#pragma unroll
            for (int r = 0; r < 4; ++r) {
                float g = accg[im][in][r];
                float u = accu[im][in][r];
                float h = g * (1.0f / (1.0f + __expf(-g))) * u;
                H[(size_t)(row + r) * INTER + col] = f2bf(h);
            }
        }
}

// ---------------- GEMM2: Out = H Wd^T, fp32 out ----------------
// Same minimum-2-phase template; 256x128 tile, 96KB dbuf LDS, 512 thr,
// grid 16x16=256 blocks = exactly 1/CU (no tail).
__global__ __launch_bounds__(512, 2) void gemm2_kernel(const unsigned short* __restrict__ Hin,
                                                       const unsigned short* __restrict__ Wd,
                                                       float* __restrict__ Out) {
    __shared__ unsigned short As[2][BM2 * BK];    // 64 KB
    __shared__ unsigned short Bs[2][BN2 * BK];    // 32 KB

    const int tid  = threadIdx.x;
    const int lane = tid & 63;
    const int wave = tid >> 6;
    int mb, nb;
    decode_block(blockIdx.x, TOKENS / BM2, HIDDEN / BN2, &mb, &nb);
    const int m0 = mb * BM2;
    const int n0 = nb * BN2;

    const int srow = tid >> 3;
    const int scol = (tid & 7) << 3;
    const int gcol = (((tid & 7) ^ (srow & 7))) << 3;

    const int wr = wave >> 1;
    const int wc = wave & 1;
    const int ln15 = lane & 15;
    const int lq = lane >> 4;
    const int swr = ln15 & 7;

    f32x4 acc[4][4];
    const f32x4 z = {0.f, 0.f, 0.f, 0.f};
    for (int i = 0; i < 4; ++i)
        for (int j = 0; j < 4; ++j) acc[i][j] = z;

    // 6 GLDS per thread per K-tile: A x4, B x2
#define STAGE2(buf, kt) do {                                                        \
        const int k0_ = (kt) * BK;                                                  \
        _Pragma("unroll")                                                           \
        for (int i_ = 0; i_ < 4; ++i_) {                                            \
            const int r_ = i_ * 64 + srow;                                          \
            GLDS(Hin + (size_t)(m0 + r_) * INTER + k0_ + gcol,                      \
                 &As[buf][r_ * BK + scol]);                                         \
        }                                                                           \
        _Pragma("unroll")                                                           \
        for (int i_ = 0; i_ < 2; ++i_) {                                            \
            const int r_ = i_ * 64 + srow;                                          \
            GLDS(Wd + (size_t)(n0 + r_) * INTER + k0_ + gcol,                       \
                 &Bs[buf][r_ * BK + scol]);                                         \
        }                                                                           \
    } while (0)

    STAGE2(0, 0);
    __syncthreads();

    for (int t = 0; t < NT2; ++t) {
        const int cur = t & 1;
        if (t + 1 < NT2) STAGE2(cur ^ 1, t + 1);
#pragma unroll
        for (int ks = 0; ks < 2; ++ks) {
            const int pofs = (((ks * 4 + lq) ^ swr)) << 3;
            bf16x8 af[4], bf[4];
#pragma unroll
            for (int im = 0; im < 4; ++im)
                af[im] = *(const bf16x8*)(&As[cur][(wr * 64 + im * 16 + ln15) * BK + pofs]);
#pragma unroll
            for (int in = 0; in < 4; ++in)
                bf[in] = *(const bf16x8*)(&Bs[cur][(wc * 64 + in * 16 + ln15) * BK + pofs]);
#pragma unroll
            for (int im = 0; im < 4; ++im)
#pragma unroll
                for (int in = 0; in < 4; ++in)
                    acc[im][in] = __builtin_amdgcn_mfma_f32_16x16x32_bf16(af[im], bf[in], acc[im][in], 0, 0, 0);
        }
        __syncthreads();
    }
#undef STAGE2

#pragma unroll
    for (int im = 0; im < 4; ++im)
#pragma unroll
        for (int in = 0; in < 4; ++in) {
            const int row = m0 + wr * 64 + im * 16 + lq * 4;
            const int col = n0 + wc * 64 + in * 16 + ln15;
#pragma unroll
            for (int r = 0; r < 4; ++r)
                Out[(size_t)(row + r) * HIDDEN + col] = acc[im][in][r];
        }
}

extern "C" void kernel_launch(void* const* d_in, const int* in_sizes, int n_in,
                              void* d_out, int out_size, void* d_ws, size_t ws_size,
                              hipStream_t stream) {
    (void)in_sizes; (void)n_in; (void)out_size; (void)ws_size;

    const float* x   = (const float*)d_in[0];
    const float* cbg = (const float*)d_in[1];
    const int*   ig  = (const int*)d_in[2];
    const float* sg  = (const float*)d_in[3];
    const float* cbu = (const float*)d_in[4];
    const int*   iu  = (const int*)d_in[5];
    const float* su  = (const float*)d_in[6];
    const float* cbd = (const float*)d_in[7];
    const int*   idn = (const int*)d_in[8];
    const float* sd  = (const float*)d_in[9];
    float* out = (float*)d_out;

    char* p = (char*)d_ws;
    unsigned short* Xb = (unsigned short*)p; p += (size_t)TOKENS * HIDDEN * 2;
    unsigned short* Wg = (unsigned short*)p; p += (size_t)INTER * HIDDEN * 2;
    unsigned short* Wu = (unsigned short*)p; p += (size_t)INTER * HIDDEN * 2;
    unsigned short* Wd = (unsigned short*)p; p += (size_t)HIDDEN * INTER * 2;
    unsigned short* H  = (unsigned short*)p; p += (size_t)TOKENS * INTER * 2;

    prep_kernel<<<dim3(528 + 2048), dim3(512), 0, stream>>>(
        x, Xb, ig, cbg, sg, Wg, iu, cbu, su, Wu, idn, cbd, sd, Wd);

    gemm1_kernel<<<dim3((TOKENS / BM1) * (INTER / BN1)), dim3(512), 0, stream>>>(Xb, Wg, Wu, H);
    gemm2_kernel<<<dim3((TOKENS / BM2) * (HIDDEN / BN2)), dim3(512), 0, stream>>>(H, Wd, out);
}

// Round 3
// 362.077 us; speedup vs baseline: 1.1772x; 1.1772x over previous
//
#include <hip/hip_runtime.h>

#define HIDDEN 2048
#define INTER  5632
#define TOKENS 4096

#define BM 128
#define BN 128
#define BK 64
#define GROUP_N 4
#define NT2 (INTER / BK)   // 88 K-tiles for gemm2

using bf16x8 = __attribute__((ext_vector_type(8))) __bf16;
using f32x4  = __attribute__((ext_vector_type(4))) float;

__device__ __forceinline__ unsigned short f2bf(float f) {
    unsigned int u = __float_as_uint(f);
    u += 0x7FFFu + ((u >> 16) & 1u);
    return (unsigned short)(u >> 16);
}

#define GLDS(gptr, lptr) \
    __builtin_amdgcn_global_load_lds((__attribute__((address_space(1))) void*)(gptr), \
                                     (__attribute__((address_space(3))) void*)(lptr), 16, 0, 0)

// ---------------- prep: dequant (LDS-cached codebook) + cast x ----------------
// R7-verified (-16 us vs divergent-gather version).
__global__ __launch_bounds__(512) void prep_kernel(
        const float* __restrict__ x, unsigned short* __restrict__ xb,
        const int* __restrict__ ig, const float* __restrict__ cbg,
        const float* __restrict__ sg, unsigned short* __restrict__ wg,
        const int* __restrict__ iu, const float* __restrict__ cbu,
        const float* __restrict__ su, unsigned short* __restrict__ wu,
        const int* __restrict__ idn, const float* __restrict__ cbd,
        const float* __restrict__ sd, unsigned short* __restrict__ wd) {
    __shared__ unsigned short cbl[4096 * 8];   // 64 KB bf16 codebook
    const int b = blockIdx.x;
    const int tid = threadIdx.x;

    if (b >= 528) {                            // ---- cast x ----
        int t = (b - 528) * 512 + tid;
        const float4* x4 = (const float4*)x;
        float4 a = x4[2 * t];
        float4 c = x4[2 * t + 1];
        uint4 o;
        o.x = f2bf(a.x) | ((unsigned int)f2bf(a.y) << 16);
        o.y = f2bf(a.z) | ((unsigned int)f2bf(a.w) << 16);
        o.z = f2bf(c.x) | ((unsigned int)f2bf(c.y) << 16);
        o.w = f2bf(c.z) | ((unsigned int)f2bf(c.w) << 16);
        ((uint4*)xb)[t] = o;
        return;
    }

    const int mat = b / 176;
    const int bl  = b % 176;
    const int* idx; const float* cb; const float* scale; unsigned short* w; int ncol8;
    if (mat == 0)      { idx = ig;  cb = cbg; scale = sg; w = wg; ncol8 = HIDDEN / 8; }
    else if (mat == 1) { idx = iu;  cb = cbu; scale = su; w = wu; ncol8 = HIDDEN / 8; }
    else               { idx = idn; cb = cbd; scale = sd; w = wd; ncol8 = INTER / 8; }

#pragma unroll
    for (int i = 0; i < 8; ++i) {
        int r = i * 512 + tid;
        const float4* c4 = (const float4*)(cb + ((size_t)r << 3));
        float4 a = c4[0];
        float4 c = c4[1];
        uint4 o;
        o.x = f2bf(a.x) | ((unsigned int)f2bf(a.y) << 16);
        o.y = f2bf(a.z) | ((unsigned int)f2bf(a.w) << 16);
        o.z = f2bf(c.x) | ((unsigned int)f2bf(c.y) << 16);
        o.w = f2bf(c.z) | ((unsigned int)f2bf(c.w) << 16);
        ((uint4*)cbl)[r] = o;
    }
    __syncthreads();

    const size_t base = (size_t)bl * 8192;
#pragma unroll 2
    for (int i = 0; i < 16; ++i) {
        size_t t = base + i * 512 + tid;
        int id = idx[t];
        float s = scale[t / ncol8];
        const unsigned short* cw = cbl + ((unsigned)id << 3);
        uint4 cv = *(const uint4*)cw;
        unsigned int ww[4];
#pragma unroll
        for (int j = 0; j < 4; ++j) {
            unsigned int pair = (&cv.x)[j];
            float lo = __uint_as_float(pair << 16) * s;
            float hi = __uint_as_float(pair & 0xFFFF0000u) * s;
            ww[j] = f2bf(lo) | ((unsigned int)f2bf(hi) << 16);
        }
        uint4 o = {ww[0], ww[1], ww[2], ww[3]};
        ((uint4*)w)[t] = o;
    }
}

// Journal:
// R2: XOR-swizzle conflict-free w/ 16x16 frags. R5: group-raster FETCH -30%.
// R8: 32x32 frags 4-way bank-conflict at BK=64 — 16x16 only. R3: (256,3)
// gemm1 spills. R4: BK=32 dbuf regressed. R6: barrier-free glds UNSAFE.
// R9 FAILED: 8-phase port (9 barriers/K-tile, 1 blk/CU): 48->31%, 176->252us.
// R10 FAILED: min-2-phase 256x128 @ 1 blk/CU: 36%, 219us. Lesson from both:
//   128KB-LDS geometries force 1 blk/CU and lose the 2-blk/CU de-phasing
//   that carries R0's 48%; per-tile vmcnt(0) drain caps depth at 1.
// R11 (this round): gemm1 REVERTED to R0-exact (verified 176us/48%).
//   gemm2 (inferred ~150us, ~25% util — the worst kernel) rebuilt as
//   counted-vmcnt dbuf pipeline KEEPING 2 blk/CU: 64KB LDS/block, grid
//   512 = exactly 2/CU zero-tail, 2 barriers/tile, head vmcnt(8) (never
//   0 in steady state), STAGE(t+2) issued under ks1 MFMA cluster.
__device__ __forceinline__ void decode_block(int bid, int nblocks_m, int nblocks_n,
                                             int* mb, int* nb) {
    int gw = nblocks_m * GROUP_N;
    int group = bid / gw;
    int inb = bid % gw;
    int gn = group * GROUP_N;
    int width = (nblocks_n - gn < GROUP_N) ? (nblocks_n - gn) : GROUP_N;
    *mb = inb / width;
    *nb = gn + inb % width;
}

// ---------------- GEMM1: H = silu(X Wg^T) * (X Wu^T), bf16 out ----------------
// R0-exact verified kernel: 128x128, 256 thr, (256,2), single-buf 2-barrier.
__global__ __launch_bounds__(256, 2) void gemm1_kernel(const unsigned short* __restrict__ X,
                                                       const unsigned short* __restrict__ Wg,
                                                       const unsigned short* __restrict__ Wu,
                                                       unsigned short* __restrict__ H) {
    __shared__ unsigned short As[BM * BK];
    __shared__ unsigned short Bgs[BN * BK];
    __shared__ unsigned short Bus[BN * BK];

    const int tid  = threadIdx.x;
    const int lane = tid & 63;
    const int wave = tid >> 6;
    int mb, nb;
    decode_block(blockIdx.x, TOKENS / BM, INTER / BN, &mb, &nb);
    const int m0 = mb * BM;
    const int n0 = nb * BN;

    const int srow = tid >> 3;
    const int scol = (tid & 7) << 3;
    const int gcol = (((tid & 7) ^ (srow & 7))) << 3;

    const int wr = wave >> 1;
    const int wc = wave & 1;
    const int ln15 = lane & 15;
    const int lq = lane >> 4;
    const int swr = ln15 & 7;

    f32x4 accg[4][4], accu[4][4];
    const f32x4 z = {0.f, 0.f, 0.f, 0.f};
    for (int i = 0; i < 4; ++i)
        for (int j = 0; j < 4; ++j) { accg[i][j] = z; accu[i][j] = z; }

    for (int kt = 0; kt < HIDDEN / BK; ++kt) {
        const int k0 = kt * BK;
        __syncthreads();
#pragma unroll
        for (int i = 0; i < 4; ++i) {
            const int r = i * 32 + srow;
            GLDS(X  + (size_t)(m0 + r) * HIDDEN + k0 + gcol, As  + r * BK + scol);
            GLDS(Wg + (size_t)(n0 + r) * HIDDEN + k0 + gcol, Bgs + r * BK + scol);
            GLDS(Wu + (size_t)(n0 + r) * HIDDEN + k0 + gcol, Bus + r * BK + scol);
        }
        __syncthreads();
#pragma unroll
        for (int ks = 0; ks < 2; ++ks) {
            bf16x8 af[4], bg[4], bu[4];
            const int pofs = (((ks * 4 + lq) ^ swr)) << 3;
#pragma unroll
            for (int im = 0; im < 4; ++im)
                af[im] = *(const bf16x8*)(As + (wr * 64 + im * 16 + ln15) * BK + pofs);
#pragma unroll
            for (int in = 0; in < 4; ++in) {
                bg[in] = *(const bf16x8*)(Bgs + (wc * 64 + in * 16 + ln15) * BK + pofs);
                bu[in] = *(const bf16x8*)(Bus + (wc * 64 + in * 16 + ln15) * BK + pofs);
            }
#pragma unroll
            for (int im = 0; im < 4; ++im)
#pragma unroll
                for (int in = 0; in < 4; ++in) {
                    accg[im][in] = __builtin_amdgcn_mfma_f32_16x16x32_bf16(af[im], bg[in], accg[im][in], 0, 0, 0);
                    accu[im][in] = __builtin_amdgcn_mfma_f32_16x16x32_bf16(af[im], bu[in], accu[im][in], 0, 0, 0);
                }
        }
    }

#pragma unroll
    for (int im = 0; im < 4; ++im)
#pragma unroll
        for (int in = 0; in < 4; ++in) {
            const int row = m0 + wr * 64 + im * 16 + lq * 4;
            const int col = n0 + wc * 64 + in * 16 + ln15;
#pragma unroll
            for (int r = 0; r < 4; ++r) {
                float g = accg[im][in][r];
                float u = accu[im][in][r];
                float h = g * (1.0f / (1.0f + __expf(-g))) * u;
                H[(size_t)(row + r) * INTER + col] = f2bf(h);
            }
        }
}

// ---------------- GEMM2: Out = H Wd^T, fp32 out ----------------
// Counted-vmcnt double-buffered pipeline @ 2 blocks/CU (R11).
__global__ __launch_bounds__(256, 2) void gemm2_kernel(const unsigned short* __restrict__ Hin,
                                                       const unsigned short* __restrict__ Wd,
                                                       float* __restrict__ Out) {
    __shared__ unsigned short As[2][BM * BK];   // 32 KB
    __shared__ unsigned short Bs[2][BN * BK];   // 32 KB

    const int tid  = threadIdx.x;
    const int lane = tid & 63;
    const int wave = tid >> 6;
    int mb, nb;
    decode_block(blockIdx.x, TOKENS / BM, HIDDEN / BN, &mb, &nb);
    const int m0 = mb * BM;
    const int n0 = nb * BN;

    const int srow = tid >> 3;
    const int scol = (tid & 7) << 3;
    const int gcol = (((tid & 7) ^ (srow & 7))) << 3;

    const int wr = wave >> 1;
    const int wc = wave & 1;
    const int ln15 = lane & 15;
    const int lq = lane >> 4;
    const int swr = ln15 & 7;

    f32x4 acc[4][4];
    const f32x4 z = {0.f, 0.f, 0.f, 0.f};
    for (int i = 0; i < 4; ++i)
        for (int j = 0; j < 4; ++j) acc[i][j] = z;

    // 8 GLDS per thread per K-tile: A x4, B x4
#define STAGE2(buf, kt) do {                                                        \
        const int k0_ = (kt) * BK;                                                  \
        _Pragma("unroll")                                                           \
        for (int i_ = 0; i_ < 4; ++i_) {                                            \
            const int r_ = i_ * 32 + srow;                                          \
            GLDS(Hin + (size_t)(m0 + r_) * INTER + k0_ + gcol,                      \
                 &As[buf][r_ * BK + scol]);                                         \
        }                                                                           \
        _Pragma("unroll")                                                           \
        for (int i_ = 0; i_ < 4; ++i_) {                                            \
            const int r_ = i_ * 32 + srow;                                          \
            GLDS(Wd + (size_t)(n0 + r_) * INTER + k0_ + gcol,                       \
                 &Bs[buf][r_ * BK + scol]);                                         \
        }                                                                           \
    } while (0)

    STAGE2(0, 0);
    STAGE2(1, 1);                       // 16 loads in flight per thread

    for (int t = 0; t < NT2; ++t) {
        const int cur = t & 1;
        // head wait: tile t's 8 loads are the oldest outstanding; keep
        // tile t+1's in flight (counted, never 0 until the last tile).
        if (t + 1 < NT2) {
            asm volatile("s_waitcnt vmcnt(8)" ::: "memory");
        } else {
            asm volatile("s_waitcnt vmcnt(0)" ::: "memory");
        }
        __builtin_amdgcn_s_barrier();   // all waves' tile-t data visible

        // ---- ks = 0: read frags, MFMA ----
        bf16x8 a0[4], b0[4];
        {
            const int pofs = ((lq ^ swr)) << 3;
#pragma unroll
            for (int im = 0; im < 4; ++im)
                a0[im] = *(const bf16x8*)(&As[cur][(wr * 64 + im * 16 + ln15) * BK + pofs]);
#pragma unroll
            for (int in = 0; in < 4; ++in)
                b0[in] = *(const bf16x8*)(&Bs[cur][(wc * 64 + in * 16 + ln15) * BK + pofs]);
        }
#pragma unroll
        for (int im = 0; im < 4; ++im)
#pragma unroll
            for (int in = 0; in < 4; ++in)
                acc[im][in] = __builtin_amdgcn_mfma_f32_16x16x32_bf16(a0[im], b0[in], acc[im][in], 0, 0, 0);

        // ---- ks = 1: read frags, then free the buffer ----
        bf16x8 a1[4], b1[4];
        {
            const int pofs = (((4 + lq) ^ swr)) << 3;
#pragma unroll
            for (int im = 0; im < 4; ++im)
                a1[im] = *(const bf16x8*)(&As[cur][(wr * 64 + im * 16 + ln15) * BK + pofs]);
#pragma unroll
            for (int in = 0; in < 4; ++in)
                b1[in] = *(const bf16x8*)(&Bs[cur][(wc * 64 + in * 16 + ln15) * BK + pofs]);
        }
        asm volatile("s_waitcnt lgkmcnt(0)" ::: "memory");  // all my LDS reads done
        __builtin_amdgcn_s_barrier();                        // everyone's reads done
        if (t + 2 < NT2) STAGE2(cur, t + 2);  // overwrite freed buf; issue hides under ks1 MFMAs
#pragma unroll
        for (int im = 0; im < 4; ++im)
#pragma unroll
            for (int in = 0; in < 4; ++in)
                acc[im][in] = __builtin_amdgcn_mfma_f32_16x16x32_bf16(a1[im], b1[in], acc[im][in], 0, 0, 0);
    }
#undef STAGE2

#pragma unroll
    for (int im = 0; im < 4; ++im)
#pragma unroll
        for (int in = 0; in < 4; ++in) {
            const int row = m0 + wr * 64 + im * 16 + lq * 4;
            const int col = n0 + wc * 64 + in * 16 + ln15;
#pragma unroll
            for (int r = 0; r < 4; ++r)
                Out[(size_t)(row + r) * HIDDEN + col] = acc[im][in][r];
        }
}

extern "C" void kernel_launch(void* const* d_in, const int* in_sizes, int n_in,
                              void* d_out, int out_size, void* d_ws, size_t ws_size,
                              hipStream_t stream) {
    (void)in_sizes; (void)n_in; (void)out_size; (void)ws_size;

    const float* x   = (const float*)d_in[0];
    const float* cbg = (const float*)d_in[1];
    const int*   ig  = (const int*)d_in[2];
    const float* sg  = (const float*)d_in[3];
    const float* cbu = (const float*)d_in[4];
    const int*   iu  = (const int*)d_in[5];
    const float* su  = (const float*)d_in[6];
    const float* cbd = (const float*)d_in[7];
    const int*   idn = (const int*)d_in[8];
    const float* sd  = (const float*)d_in[9];
    float* out = (float*)d_out;

    char* p = (char*)d_ws;
    unsigned short* Xb = (unsigned short*)p; p += (size_t)TOKENS * HIDDEN * 2;
    unsigned short* Wg = (unsigned short*)p; p += (size_t)INTER * HIDDEN * 2;
    unsigned short* Wu = (unsigned short*)p; p += (size_t)INTER * HIDDEN * 2;
    unsigned short* Wd = (unsigned short*)p; p += (size_t)HIDDEN * INTER * 2;
    unsigned short* H  = (unsigned short*)p; p += (size_t)TOKENS * INTER * 2;

    prep_kernel<<<dim3(528 + 2048), dim3(512), 0, stream>>>(
        x, Xb, ig, cbg, sg, Wg, iu, cbu, su, Wu, idn, cbd, sd, Wd);

    gemm1_kernel<<<dim3((TOKENS / BM) * (INTER / BN)), dim3(256), 0, stream>>>(Xb, Wg, Wu, H);
    gemm2_kernel<<<dim3((TOKENS / BM) * (HIDDEN / BN)), dim3(256), 0, stream>>>(H, Wd, out);
}